// Round 4
// baseline (509.559 us; speedup 1.0000x reference)
//
#include <hip/hip_runtime.h>
#include <math.h>

// Quantized ConvBlock, round 7: occupancy attack on conv_main.
//   R1-R3 analysis: 2 blocks/CU (reg+LDS limited) = 2 waves/SIMD, barrier-aligned ->
//   LDS-read and MFMA windows serialize (serial pipe sum reproduces ~160 us; overlapped
//   max ~62 us). Fix: 32o x 16h x 32w blocks (acc 128->64 regs), weights moved from LDS
//   to per-wave coalesced global loads out of L2-resident wq_b (LDS 80->41 KB) ->
//   __launch_bounds__(256,3): 3 blocks/CU = 12 waves/CU = 3 waves/SIMD.
//   Chunk boundary keeps R5's T4 (barrier; stage 5 gl_lds; vmcnt(5); barrier).
//   R1's LDS swizzle removed: consecutive-chunk reads are conflict-free already
//   (counter was flat 1.1e7->1.26e7 under the swizzle).
//
// ws layout (bytes):
//   0        : xmax bits (uint)             [memset to 0]
//   256      : fw[256] floats
//   2048     : wq_a  f16 [o][tap][c]        (fallback layout)
//   655360   : wq_b  f16 [cc][tap][o][c16]  (linear; conv reads via L2)
//   1572864  : ZP zero page (2 KB, memset)
//   2097152  : xq    f16 [n][cc][h][w][c16]

#define FW_NUM 20017.23017802413f
#define FX_NUM 835.5924988699913f
#define WQA_OFF 2048
#define WQB_OFF (640 * 1024)
#define ZP_OFF  (1536 * 1024)
#define XQ_OFF  (2 * 1024 * 1024)
#define XQ_BYTES 67108864ull

// fallback-kernel tile params (R2 kernel, kept verbatim)
#define CK  16
#define CKP 24
#define JW  130

typedef _Float16 half8 __attribute__((ext_vector_type(8)));
typedef _Float16 half4 __attribute__((ext_vector_type(4)));
typedef float floatx16 __attribute__((ext_vector_type(16)));

__device__ __forceinline__ void gl_lds16(const void* g, void* s) {
    __builtin_amdgcn_global_load_lds((const __attribute__((address_space(1))) void*)g,
                                     (__attribute__((address_space(3))) void*)s, 16, 0, 0);
}

__global__ void xmax_kernel(const float* __restrict__ x, unsigned int* wsu, int n4) {
    int tid = blockIdx.x * blockDim.x + threadIdx.x;
    int stride = gridDim.x * blockDim.x;
    const float4* x4 = (const float4*)x;
    float m = 0.f;
    for (int i = tid; i < n4; i += stride) {
        float4 v = x4[i];
        m = fmaxf(m, fmaxf(fmaxf(fabsf(v.x), fabsf(v.y)), fmaxf(fabsf(v.z), fabsf(v.w))));
    }
    #pragma unroll
    for (int off = 32; off >= 1; off >>= 1)
        m = fmaxf(m, __shfl_down(m, off, 64));
    __shared__ float sm[4];
    if ((threadIdx.x & 63) == 0) sm[threadIdx.x >> 6] = m;
    __syncthreads();
    if (threadIdx.x == 0) {
        m = fmaxf(fmaxf(sm[0], sm[1]), fmaxf(sm[2], sm[3]));
        atomicMax(wsu, __float_as_uint(m));
    }
}

// one block per o (256 blocks, 128 threads; t = input channel c)
__global__ void wq_kernel(const float* __restrict__ W, float* wsf, int big) {
    int o = blockIdx.x;
    int t = threadIdx.x;
    const float* wrow = W + o * 1152;
    float wv[9];
    float s = 0.f;
    #pragma unroll
    for (int k = 0; k < 9; k++) { wv[k] = wrow[t * 9 + k]; s += fabsf(wv[k]); }
    #pragma unroll
    for (int off = 32; off >= 1; off >>= 1) s += __shfl_down(s, off, 64);
    __shared__ float sred[2];
    __shared__ float sfw;
    if ((t & 63) == 0) sred[t >> 6] = s;
    __syncthreads();
    if (t == 0) {
        float wsum = sred[0] + sred[1];
        if (wsum == 0.f) wsum = 1.f;
        float fw = FW_NUM / wsum;
        wsf[64 + o] = fw;
        sfw = fw;
    }
    __syncthreads();
    float fw = sfw;
    _Float16* wqa = (_Float16*)((char*)wsf + WQA_OFF);   // [o][tap][c]
    _Float16* wqb = (_Float16*)((char*)wsf + WQB_OFF);   // [cc][tap][o][c16] linear
    #pragma unroll
    for (int k = 0; k < 9; k++) {
        _Float16 hv = (_Float16)rintf(wv[k] * fw);       // rintf = RNE = jnp.round
        wqa[(o * 9 + k) * 128 + t] = hv;
        if (big)
            wqb[(((t >> 4) * 9 + k) * 256 + o) * 16 + (t & 15)] = hv;
    }
}

// block = one (n, cc, h): quantize 16 c-planes' row h into [w][c16] (4 KB contiguous)
__global__ void quantx_kernel(const float* __restrict__ x, const float* __restrict__ wsf,
                              _Float16* __restrict__ xq) {
    int bid = blockIdx.x;           // (n*8 + cc)*128 + h
    int h  = bid & 127;
    int cc = (bid >> 7) & 7;
    int n  = bid >> 10;
    float xmax = __uint_as_float(((const unsigned int*)wsf)[0]);
    float fx = xmax > 0.f ? FX_NUM / xmax : 1.0f;
    int w = threadIdx.x;            // 128
    const float* xp = x + ((size_t)(n * 128 + cc * 16) * 128 + h) * 128 + w;
    half8 v0, v1;
    #pragma unroll
    for (int ci = 0; ci < 8; ci++)  v0[ci] = (_Float16)rintf(fx * xp[(size_t)ci * 16384]);
    #pragma unroll
    for (int ci = 8; ci < 16; ci++) v1[ci - 8] = (_Float16)rintf(fx * xp[(size_t)ci * 16384]);
    _Float16* op = xq + ((size_t)bid * 128 + w) * 16;
    *(half8*)op = v0;
    *(half8*)(op + 8) = v1;
}

__global__ __launch_bounds__(256, 3) void conv_main(const _Float16* __restrict__ xq,
                                                    const float* __restrict__ bias,
                                                    const float* __restrict__ wsf,
                                                    float* __restrict__ out) {
    // xs: 18 rows x 68 slots(16B) = 19584 B, padded to 20480 B per buffer (staging
    //   writes slots 0..1279; slots >= 1224 are ZP-sourced pad). Linear layout:
    //   slot = r*68 + spi; spi 0..67 -> input w = w0 + (spi>>1) - 1, c-half = spi&1.
    __shared__ __align__(16) _Float16 xs[2][10240];   // 40960 B
    __shared__ float sc[32], bz[32];                  // total 41216 B -> 3 blk/CU

    float xmax = __uint_as_float(((const unsigned int*)wsf)[0]);
    float fx = xmax > 0.f ? FX_NUM / xmax : 1.0f;

    // XCD-contiguous remap (4096 % 8 == 0 -> bijective); o fastest-varying so one XCD
    // serves all 8 o-blocks of a pixel tile (x reuse) + neighboring tiles (halo reuse).
    int bx0 = blockIdx.x;
    int bx = (bx0 & 7) * 512 + (bx0 >> 3);
    int o0 = (bx & 7) << 5;
    int w0 = ((bx >> 3) & 3) << 5;
    int h0 = ((bx >> 5) & 7) << 4;
    int n  = bx >> 8;

    int tid = threadIdx.x;
    int lane = tid & 63;
    int wv = tid >> 6;
    int m32 = lane & 31;
    int q2 = lane >> 5;

    const char* wsb = (const char*)wsf;

    // ---- per-wave staging: 5 gl_lds of 1024 B each (slots s = wv + 4k, k = 0..4)
    int goff[5];
    int gstr[5];
    #pragma unroll
    for (int k = 0; k < 5; ++k) {
        int s = wv + 4 * k;                  // 0..19
        int slot = s * 64 + lane;            // 0..1279
        int r = (slot * 241) >> 14;          // exact /68 for slot < 1224
        int spi = slot - r * 68;
        int h = h0 + r - 1;
        int w = w0 + (spi >> 1) - 1;
        bool ok = (slot < 1224) && (h >= 0) && (h < 128) && (w >= 0) && (w < 128);
        if (ok) {
            goff[k] = XQ_OFF + n * 4194304 + (h * 128 + w) * 32 + (spi & 1) * 16;
            gstr[k] = 524288;                // next c-chunk plane
        } else {
            goff[k] = ZP_OFF + lane * 16;
            gstr[k] = 0;
        }
    }
    auto stage = [&](int tb) {
        #pragma unroll
        for (int k = 0; k < 5; ++k) {
            int s = wv + 4 * k;
            gl_lds16(wsb + goff[k], (char*)&xs[tb][0] + s * 1024);
            goff[k] += gstr[k];
        }
    };

    // ---- scale/bias to LDS (read only in epilogue; ordered by K-loop barriers)
    if (tid < 32) {
        float fwv = wsf[64 + o0 + tid];
        sc[tid] = 1.0f / (fx * fwv);
        bz[tid] = bias[o0 + tid];
    }

    floatx16 acc[4];
    #pragma unroll
    for (int p = 0; p < 4; ++p)
        #pragma unroll
        for (int e = 0; e < 16; ++e) acc[p][e] = 0.f;

    // ---- prologue: stage chunk 0 into buffer 0
    stage(0);

    // ---- K loop: 8 chunks of 16 c; weights read per-wave from L2 (wq_b), 1 kw-group ahead
    for (int cc = 0; cc < 8; ++cc) {
        int cb = cc & 1;
        __builtin_amdgcn_s_barrier();        // all waves done reading buf cb^1
        if (cc < 7) {
            stage(cb ^ 1);                   // 5 loads: chunk cc+1 -> other buffer
            asm volatile("s_waitcnt vmcnt(5)" ::: "memory");   // chunk cc's stage retired
        } else {
            asm volatile("s_waitcnt vmcnt(0)" ::: "memory");
        }
        __builtin_amdgcn_s_barrier();        // buf cb valid for everyone

        const char* xb = (const char*)&xs[cb][0] + wv * (4 * 1088);
        const char* wq_c = wsb + WQB_OFF + (size_t)cc * 73728 + (o0 + m32) * 32 + q2 * 16;

        half8 wfA[3], wfB[3];
        #pragma unroll
        for (int kh = 0; kh < 3; ++kh)       // kw=0 group: 3 coalesced 1024B wave-loads
            wfA[kh] = *(const half8*)(wq_c + (kh * 3 + 0) * 8192);

        #pragma unroll
        for (int kw = 0; kw < 3; ++kw) {
            half8 xf[6];
            #pragma unroll
            for (int srow = 0; srow < 6; ++srow)
                xf[srow] = *(const half8*)(xb + srow * 1088 + (m32 + kw) * 32 + q2 * 16);
            if (kw < 2) {                    // prefetch next kw group under this MFMA cluster
                #pragma unroll
                for (int kh = 0; kh < 3; ++kh) {
                    if (kw & 1) wfA[kh] = *(const half8*)(wq_c + (kh * 3 + kw + 1) * 8192);
                    else        wfB[kh] = *(const half8*)(wq_c + (kh * 3 + kw + 1) * 8192);
                }
            }
            __builtin_amdgcn_s_setprio(1);
            #pragma unroll
            for (int kh = 0; kh < 3; ++kh) {
                half8 wcur = (kw & 1) ? wfB[kh] : wfA[kh];
                #pragma unroll
                for (int p = 0; p < 4; ++p)
                    acc[p] = __builtin_amdgcn_mfma_f32_32x32x16_f16(wcur, xf[p + kh], acc[p], 0, 0, 0);
            }
            __builtin_amdgcn_s_setprio(0);
        }
    }

    // ---- epilogue: D row = o (reg), col = pixel (lane) -> coalesced stores
    #pragma unroll
    for (int e = 0; e < 16; ++e) {
        int o_loc = (e & 3) + 8 * (e >> 2) + 4 * q2;
        float scale = sc[o_loc];
        float bv = bz[o_loc];
        #pragma unroll
        for (int p = 0; p < 4; ++p) {
            int h = h0 + wv * 4 + p;
            float v = fmaxf(fmaf(acc[p][e], scale, bv), 0.f);
            out[(((size_t)(n * 256 + o0 + o_loc)) * 128 + h) * 128 + w0 + m32] = v;
        }
    }
}

// ---------------- fallback (R2 kernel, used if ws too small) ----------------
__global__ __launch_bounds__(256, 2) void conv_fallback(const float* __restrict__ x,
                                                        const float* __restrict__ bias,
                                                        const float* __restrict__ wsf,
                                                        float* __restrict__ out) {
    __shared__ __align__(16) _Float16 xs[6 * JW * CKP];
    __shared__ __align__(16) _Float16 wlds[9 * 64 * CKP];

    const unsigned int* wsu = (const unsigned int*)wsf;
    float xmax = __uint_as_float(wsu[0]);
    float fx = xmax > 0.f ? FX_NUM / xmax : 1.0f;

    int bx = blockIdx.x;
    int n  = bx >> 5;
    int h0 = (bx & 31) << 2;
    int o0 = blockIdx.y << 6;

    int tid  = threadIdx.x;
    int lane = tid & 63;
    int wave = tid >> 6;
    int m32  = lane & 31;
    int q2   = lane >> 5;

    const _Float16* wq16 = (const _Float16*)((const char*)wsf + WQA_OFF);
    const float* xn = x + (size_t)n * (128 * 128 * 128);

    floatx16 acc[4][2];
    #pragma unroll
    for (int mt = 0; mt < 4; mt++)
        #pragma unroll
        for (int nt = 0; nt < 2; nt++)
            #pragma unroll
            for (int e = 0; e < 16; e++) acc[mt][nt][e] = 0.f;

    if (tid < 192) {
        int r = tid >> 5;
        int s = tid & 31;
        int c = s & 15;
        int j = (s >> 4) ? (JW - 1) : 0;
        xs[(r * JW + j) * CKP + c] = (_Float16)0.f;
    }

    for (int c0 = 0; c0 < 128; c0 += CK) {
        __syncthreads();
        #pragma unroll
        for (int it = 0; it < 12; ++it) {
            int idx = tid + it * 256;
            int j  = (idx & 127) + 1;
            int c4 = (idx >> 7) & 3;
            int r  = idx >> 9;
            int h  = h0 + r - 1;
            float v0 = 0.f, v1 = 0.f, v2 = 0.f, v3 = 0.f;
            if (h >= 0 && h < 128) {
                const float* xp = xn + (size_t)(c0 + c4 * 4) * 16384 + h * 128 + (j - 1);
                v0 = xp[0]; v1 = xp[16384]; v2 = xp[32768]; v3 = xp[49152];
            }
            half4 hv;
            hv[0] = (_Float16)rintf(fx * v0);
            hv[1] = (_Float16)rintf(fx * v1);
            hv[2] = (_Float16)rintf(fx * v2);
            hv[3] = (_Float16)rintf(fx * v3);
            *(half4*)&xs[(r * JW + j) * CKP + c4 * 4] = hv;
        }
        #pragma unroll
        for (int it = 0; it < 5; ++it) {
            int idx = tid + it * 256;
            if (idx < 1152) {
                int o   = idx / 18;
                int rem = idx - o * 18;
                int tap = rem >> 1;
                int g   = rem & 1;
                half8 v = *(const half8*)(wq16 + ((size_t)(o0 + o) * 9 + tap) * 128 + c0 + g * 8);
                *(half8*)&wlds[(tap * 64 + o) * CKP + g * 8] = v;
            }
        }
        __syncthreads();

        const _Float16* xbase = &xs[(wave * JW + m32) * CKP + q2 * 8];
        const _Float16* wbase = &wlds[m32 * CKP + q2 * 8];
        #pragma unroll
        for (int kh = 0; kh < 3; ++kh) {
            #pragma unroll
            for (int kw = 0; kw < 3; ++kw) {
                int tap = kh * 3 + kw;
                half8 b0 = *(const half8*)(wbase + (tap * 64 +  0) * CKP);
                half8 b1 = *(const half8*)(wbase + (tap * 64 + 32) * CKP);
                #pragma unroll
                for (int mt = 0; mt < 4; ++mt) {
                    half8 a = *(const half8*)(xbase + (kh * JW + kw + mt * 32) * CKP);
                    acc[mt][0] = __builtin_amdgcn_mfma_f32_32x32x16_f16(a, b0, acc[mt][0], 0, 0, 0);
                    acc[mt][1] = __builtin_amdgcn_mfma_f32_32x32x16_f16(a, b1, acc[mt][1], 0, 0, 0);
                }
            }
        }
    }

    int h = h0 + wave;
    #pragma unroll
    for (int nt = 0; nt < 2; ++nt) {
        int o = o0 + nt * 32 + m32;
        float fwv = wsf[64 + o];
        float scale = 1.0f / (fx * fwv);
        float bv = bias[o];
        float* op = out + (((size_t)n * 256 + o) * 128 + h) * 128;
        #pragma unroll
        for (int mt = 0; mt < 4; ++mt) {
            #pragma unroll
            for (int g = 0; g < 4; ++g) {
                int w = mt * 32 + 8 * g + 4 * q2;
                float4 r;
                r.x = fmaxf(fmaf(acc[mt][nt][4 * g + 0], scale, bv), 0.f);
                r.y = fmaxf(fmaf(acc[mt][nt][4 * g + 1], scale, bv), 0.f);
                r.z = fmaxf(fmaf(acc[mt][nt][4 * g + 2], scale, bv), 0.f);
                r.w = fmaxf(fmaf(acc[mt][nt][4 * g + 3], scale, bv), 0.f);
                *(float4*)(op + w) = r;
            }
        }
    }
}

extern "C" void kernel_launch(void* const* d_in, const int* in_sizes, int n_in,
                              void* d_out, int out_size, void* d_ws, size_t ws_size,
                              hipStream_t stream) {
    const float* x = (const float*)d_in[0];   // [16,128,128,128]
    const float* W = (const float*)d_in[1];   // [256,128,3,3]
    const float* b = (const float*)d_in[2];   // [256]
    float* out = (float*)d_out;
    float* wsf = (float*)d_ws;

    int big = (ws_size >= (size_t)XQ_OFF + XQ_BYTES) ? 1 : 0;

    hipMemsetAsync(d_ws, 0, 256, stream);     // xmax slot (ws poisoned 0xAA)
    if (big)
        hipMemsetAsync((char*)d_ws + ZP_OFF, 0, 2048, stream);   // zero page for OOB staging

    xmax_kernel<<<1024, 256, 0, stream>>>(x, (unsigned int*)d_ws, (16 * 128 * 128 * 128) / 4);
    wq_kernel<<<256, 128, 0, stream>>>(W, wsf, big);

    if (big) {
        _Float16* xq = (_Float16*)((char*)d_ws + XQ_OFF);
        quantx_kernel<<<16 * 8 * 128, 128, 0, stream>>>(x, wsf, xq);
        conv_main<<<4096, 256, 0, stream>>>(xq, b, wsf, out);
    } else {
        dim3 grid(512, 4);
        conv_fallback<<<grid, 256, 0, stream>>>(x, b, wsf, out);
    }
}